// Round 14
// baseline (1093.001 us; speedup 1.0000x reference)
//
#include <hip/hip_runtime.h>

// Problem constants (from reference setup_inputs).
constexpr int kN = 1000000;   // rows
constexpr int kF = 128;       // features
constexpr int kB = 4096;      // batches

using short8 = __attribute__((ext_vector_type(8))) short;
using f32x4 = __attribute__((ext_vector_type(4))) float;

__device__ __forceinline__ unsigned short to_bf16(float f) {
  unsigned int u = __builtin_bit_cast(unsigned int, f);
  u += 0x7fffu + ((u >> 16) & 1u);  // RNE
  return (unsigned short)(u >> 16);
}

// One packed RNE f32->bf16 pair (lo -> bits[15:0], hi -> bits[31:16]).
__device__ __forceinline__ unsigned int cvt_pk_bf16(float lo, float hi) {
  unsigned int r;
  asm("v_cvt_pk_bf16_f32 %0, %1, %2" : "=v"(r) : "v"(lo), "v"(hi));
  return r;
}

__device__ __forceinline__ float silu_f(float z) {
  return z / (1.f + __expf(-z));
}

// ---------------- K0b: pre-permute W2 fragments to global bf16 ----------------
// Same pair-perm mapping as the W1 LDS fill: n-blocks 2q,2q+1 <-> rows
// 32q + 2cc + {0,1}. Fragment idx -> (nb,kb,lane,i); read is lane-linear b128.
__global__ __launch_bounds__(256) void k_prepw(const float* __restrict__ W2,
                                               unsigned short* __restrict__ w2p) {
  const int idx = blockIdx.x * 256 + threadIdx.x;  // 16384 total
  const int i = idx & 7;
  const int l = (idx >> 3) & 63;
  const int kb = (idx >> 9) & 3;
  const int nb = (idx >> 11) & 7;
  const int cc = l & 15;
  const int col = kb * 32 + ((l >> 4) & 3) * 8 + i;
  const int row = (nb >> 1) * 32 + 2 * cc + (nb & 1);
  w2p[idx] = to_bf16(W2[row * kF + col]);
}

// ---------------- K1: per-batch precompute ----------------
__global__ __launch_bounds__(128) void k_precompute(
    const float* __restrict__ E, const float* __restrict__ Wq,
    const float* __restrict__ bq, const float* __restrict__ Wk,
    const float* __restrict__ Wv, float* __restrict__ u,
    float* __restrict__ v, float* __restrict__ cb,
    float* __restrict__ anorm) {
  __shared__ float ksh[kF];
  const int b = blockIdx.x;
  const int f = threadIdx.x;
  const float Eb = E[b];
  const float e0 = fmaxf(Eb, 0.f);
  const float e1 = fmaxf(-Eb, 0.f);
  const float en0 = e0 / fmaxf(e0, 1.f);
  const float en1 = e1 / fmaxf(e1, 1.f);
  const float kf = Wk[2 * f + 0] * en0 + Wk[2 * f + 1] * en1;
  const float vf = Wv[2 * f + 0] * e0 + Wv[2 * f + 1] * e1;
  v[b * kF + f] = vf;
  ksh[f] = kf;
  __syncthreads();
  float uj = 0.f;
#pragma unroll 8
  for (int ff = 0; ff < kF; ++ff) uj = fmaf(Wq[ff * kF + f], ksh[ff], uj);
  u[b * kF + f] = uj;
  if (f == 0) {
    float c = 0.f;
    for (int ff = 0; ff < kF; ++ff) c = fmaf(bq[ff], ksh[ff], c);
    cb[b] = c;
    anorm[b] = 0.f;
  }
}

// ---------------- K2: dot -> softplus -> segment sum ----------------
// 16 rows per wave-iteration (4 quads); per-group run accumulators.
__global__ __launch_bounds__(256) void k_pass1(
    const float* __restrict__ x, const int* __restrict__ seg,
    const float* __restrict__ u, const float* __restrict__ cb,
    float* __restrict__ a, float* __restrict__ anorm) {
  const int lane = threadIdx.x & 63;
  const int g = lane >> 4;   // row within quad
  const int c = lane & 15;   // column chunk (8 floats)
  const int wave = (int)((blockIdx.x * blockDim.x + threadIdx.x) >> 6);
  const int nw = (int)((gridDim.x * blockDim.x) >> 6);
  const int cpw = (((kN + nw - 1) / nw) + 15) & ~15;  // multiple of 16
  const int r0 = wave * cpw;
  const int r1 = min(kN, r0 + cpw);
  int bacc = -1;
  float ssum = 0.f;
  for (int rb = r0; rb < r1; rb += 16) {
    float4 xa[4], xb[4], ua[4], ub[4];
    int b4[4];
#pragma unroll
    for (int q = 0; q < 4; ++q) {
      const int row = rb + 4 * q + g;
      const int b = seg[row];
      b4[q] = b;
      const float* xr = x + (size_t)row * kF + c * 8;
      const float* ur = u + (size_t)b * kF + c * 8;
      xa[q] = *reinterpret_cast<const float4*>(xr);
      xb[q] = *reinterpret_cast<const float4*>(xr + 4);
      ua[q] = *reinterpret_cast<const float4*>(ur);
      ub[q] = *reinterpret_cast<const float4*>(ur + 4);
    }
    float av4[4];
#pragma unroll
    for (int q = 0; q < 4; ++q) {
      float p = xa[q].x * ua[q].x;
      p = fmaf(xa[q].y, ua[q].y, p);
      p = fmaf(xa[q].z, ua[q].z, p);
      p = fmaf(xa[q].w, ua[q].w, p);
      p = fmaf(xb[q].x, ub[q].x, p);
      p = fmaf(xb[q].y, ub[q].y, p);
      p = fmaf(xb[q].z, ub[q].z, p);
      p = fmaf(xb[q].w, ub[q].w, p);
#pragma unroll
      for (int o = 1; o < 16; o <<= 1) p += __shfl_xor(p, o);
      const float dot = (p + cb[b4[q]]) * 0.08838834764831845f;  // 1/sqrt(128)
      const float av = fmaxf(dot, 0.f) + __logf(1.f + __expf(-fabsf(dot)));
      av4[q] = av;
      if (c == 0) a[rb + 4 * q + g] = av;
    }
    if (c == 0) {
#pragma unroll
      for (int q = 0; q < 4; ++q) {
        if (b4[q] != bacc) {
          if (bacc >= 0) atomicAdd(anorm + bacc, ssum);
          bacc = b4[q];
          ssum = 0.f;
        }
        ssum += av4[q];
      }
    }
  }
  if (c == 0 && bacc >= 0) atomicAdd(anorm + bacc, ssum);
}

// ---------------- K3: attn*v + residual MLP via bf16 MFMA ----------------
// R13 structure, but W2 evicted from LDS (read from pre-permuted global
// copy, L2/L1-resident, lane-linear b128 loads). LDS/block = 32KB W1 +
// 10KB stg = 42KB -> 3 blocks/CU -> 24 waves/CU. __launch_bounds__(512,6)
// caps VGPR at 85 (natural was 84).
constexpr int kWaves = 8;        // 512 threads
constexpr int kStg = 40;         // staging row stride in bf16

__global__ __launch_bounds__(512, 6) void k_pass2(
    const int* __restrict__ seg, const float* __restrict__ a,
    const float* __restrict__ anorm, const float* __restrict__ v,
    const float* __restrict__ W1, const unsigned short* __restrict__ w2p,
    float* __restrict__ out) {
  __shared__ __align__(16) unsigned short Wf[16384];
  __shared__ __align__(16) unsigned short stg[kWaves][16 * kStg];
  const int tid = threadIdx.x;
  for (int idx = tid; idx < 16384; idx += 512) {
    const int i = idx & 7;
    const int l = (idx >> 3) & 63;
    const int kb = (idx >> 9) & 3;
    const int nb = (idx >> 11) & 7;
    const int cc = l & 15;
    const int col = kb * 32 + ((l >> 4) & 3) * 8 + i;
    const int row = (nb >> 1) * 32 + 2 * cc + (nb & 1);  // pair perm
    Wf[idx] = to_bf16(W1[row * kF + col]);
  }
  __syncthreads();

  const int wid = tid >> 6;
  const int lane = tid & 63;
  const int c = lane & 15;
  const int g = lane >> 4;
  unsigned short* __restrict__ st = stg[wid];

  const int gw = blockIdx.x * kWaves + wid;
  const int nw = gridDim.x * kWaves;
  const int niter = kN / 32;  // 31250

  for (int it = gw; it < niter; it += nw) {
    const int rbase = it * 32;
    const int blo = seg[rbase];
    const int bhi = seg[rbase + 31];
    const bool uni = (blo == bhi);   // wave-uniform branch

    int bb[2];
    float attn[2];
    short8 t1[2][4];
    float2 vep[4];  // uniform-path epilogue v pairs (cols 32q+2c+{0,1})

    if (uni) {
      const float an = anorm[blo] + 1e-8f;
      const float* vrow = v + (size_t)blo * kF;
      float4 va[4], vb[4];
#pragma unroll
      for (int kb = 0; kb < 4; ++kb) {
        const int k0 = kb * 32 + g * 8;
        va[kb] = *reinterpret_cast<const float4*>(vrow + k0);
        vb[kb] = *reinterpret_cast<const float4*>(vrow + k0 + 4);
      }
#pragma unroll
      for (int q = 0; q < 4; ++q)
        vep[q] = *reinterpret_cast<const float2*>(vrow + q * 32 + 2 * c);
#pragma unroll
      for (int mt = 0; mt < 2; ++mt) {
        const int row = rbase + mt * 16 + c;
        const float at = a[row] / an;
        attn[mt] = at;
        bb[mt] = blo;
#pragma unroll
        for (int kb = 0; kb < 4; ++kb) {
          uint4 pk;
          pk.x = cvt_pk_bf16(silu_f(at * va[kb].x), silu_f(at * va[kb].y));
          pk.y = cvt_pk_bf16(silu_f(at * va[kb].z), silu_f(at * va[kb].w));
          pk.z = cvt_pk_bf16(silu_f(at * vb[kb].x), silu_f(at * vb[kb].y));
          pk.w = cvt_pk_bf16(silu_f(at * vb[kb].z), silu_f(at * vb[kb].w));
          t1[mt][kb] = __builtin_bit_cast(short8, pk);
        }
      }
    } else {
#pragma unroll
      for (int mt = 0; mt < 2; ++mt) {
        const int row = rbase + mt * 16 + c;
        const int b = seg[row];
        bb[mt] = b;
        const float at = a[row] / (anorm[b] + 1e-8f);
        attn[mt] = at;
        const float* vrow = v + (size_t)b * kF;
#pragma unroll
        for (int kb = 0; kb < 4; ++kb) {
          const int k0 = kb * 32 + g * 8;
          const float4 va = *reinterpret_cast<const float4*>(vrow + k0);
          const float4 vb = *reinterpret_cast<const float4*>(vrow + k0 + 4);
          uint4 pk;
          pk.x = cvt_pk_bf16(silu_f(at * va.x), silu_f(at * va.y));
          pk.y = cvt_pk_bf16(silu_f(at * va.z), silu_f(at * va.w));
          pk.z = cvt_pk_bf16(silu_f(at * vb.x), silu_f(at * vb.y));
          pk.w = cvt_pk_bf16(silu_f(at * vb.z), silu_f(at * vb.w));
          t1[mt][kb] = __builtin_bit_cast(short8, pk);
        }
      }
    }

    f32x4 acc2[2][8];
#pragma unroll
    for (int mt = 0; mt < 2; ++mt)
#pragma unroll
      for (int jb = 0; jb < 8; ++jb) acc2[mt][jb] = (f32x4){0.f, 0.f, 0.f, 0.f};

    __builtin_amdgcn_s_setprio(1);
#pragma unroll
    for (int p = 0; p < 4; ++p) {
      f32x4 z[2][2];
#pragma unroll
      for (int mt = 0; mt < 2; ++mt)
#pragma unroll
        for (int nb = 0; nb < 2; ++nb) z[mt][nb] = (f32x4){0.f, 0.f, 0.f, 0.f};
#pragma unroll
      for (int kb = 0; kb < 4; ++kb) {
        const short8 w0 = *reinterpret_cast<const short8*>(
            &Wf[(((2 * p + 0) * 4 + kb) * 64 + lane) * 8]);
        const short8 w1 = *reinterpret_cast<const short8*>(
            &Wf[(((2 * p + 1) * 4 + kb) * 64 + lane) * 8]);
        z[0][0] = __builtin_amdgcn_mfma_f32_16x16x32_bf16(t1[0][kb], w0,
                                                          z[0][0], 0, 0, 0);
        z[0][1] = __builtin_amdgcn_mfma_f32_16x16x32_bf16(t1[0][kb], w1,
                                                          z[0][1], 0, 0, 0);
        z[1][0] = __builtin_amdgcn_mfma_f32_16x16x32_bf16(t1[1][kb], w0,
                                                          z[1][0], 0, 0, 0);
        z[1][1] = __builtin_amdgcn_mfma_f32_16x16x32_bf16(t1[1][kb], w1,
                                                          z[1][1], 0, 0, 0);
      }
      // stage mt's t2 tile (features 32p+2c,+1 -> one u32), read A-frag,
      // then overwrite with the next mt (same-wave DS ops are in-order).
      short8 t2f[2];
#pragma unroll
      for (int mt = 0; mt < 2; ++mt) {
#pragma unroll
        for (int r = 0; r < 4; ++r) {
          const unsigned int pk =
              cvt_pk_bf16(silu_f(z[mt][0][r]), silu_f(z[mt][1][r]));
          *reinterpret_cast<unsigned int*>(
              &st[(g * 4 + r) * kStg + 2 * c]) = pk;
        }
        t2f[mt] =
            *reinterpret_cast<const short8*>(&st[c * kStg + g * 8]);
      }
#pragma unroll
      for (int jb = 0; jb < 8; ++jb) {
        const short8 w2f = *reinterpret_cast<const short8*>(
            &w2p[((jb * 4 + p) * 64 + lane) * 8]);
        acc2[0][jb] = __builtin_amdgcn_mfma_f32_16x16x32_bf16(t2f[0], w2f,
                                                              acc2[0][jb], 0, 0, 0);
        acc2[1][jb] = __builtin_amdgcn_mfma_f32_16x16x32_bf16(t2f[1], w2f,
                                                              acc2[1][jb], 0, 0, 0);
      }
    }
    __builtin_amdgcn_s_setprio(0);

    // epilogue: acc2[2q],acc2[2q+1] -> cols 32q+2c,32q+2c+1 (dwordx2 stores)
    if (uni) {
#pragma unroll
      for (int mt = 0; mt < 2; ++mt) {
#pragma unroll
        for (int r = 0; r < 4; ++r) {
          const float at4 = __shfl(attn[mt], g * 4 + r);
          const int row = rbase + mt * 16 + g * 4 + r;
          float* orow = out + (size_t)row * kF;
#pragma unroll
          for (int q = 0; q < 4; ++q) {
            float2 o;
            o.x = fmaf(at4, vep[q].x, acc2[mt][2 * q + 0][r]);
            o.y = fmaf(at4, vep[q].y, acc2[mt][2 * q + 1][r]);
            *reinterpret_cast<float2*>(orow + q * 32 + 2 * c) = o;
          }
        }
      }
    } else {
#pragma unroll
      for (int mt = 0; mt < 2; ++mt) {
#pragma unroll
        for (int r = 0; r < 4; ++r) {
          const int b4 = __shfl(bb[mt], g * 4 + r);
          const float at4 = __shfl(attn[mt], g * 4 + r);
          const float* vr = v + (size_t)b4 * kF;
          const int row = rbase + mt * 16 + g * 4 + r;
          float* orow = out + (size_t)row * kF;
#pragma unroll
          for (int q = 0; q < 4; ++q) {
            const float2 vv =
                *reinterpret_cast<const float2*>(vr + q * 32 + 2 * c);
            float2 o;
            o.x = fmaf(at4, vv.x, acc2[mt][2 * q + 0][r]);
            o.y = fmaf(at4, vv.y, acc2[mt][2 * q + 1][r]);
            *reinterpret_cast<float2*>(orow + q * 32 + 2 * c) = o;
          }
        }
      }
    }
  }
}

extern "C" void kernel_launch(void* const* d_in, const int* in_sizes, int n_in,
                              void* d_out, int out_size, void* d_ws,
                              size_t ws_size, hipStream_t stream) {
  const float* x = (const float*)d_in[0];
  const float* E = (const float*)d_in[1];
  const int* seg = (const int*)d_in[3];
  const float* Wq = (const float*)d_in[4];
  const float* bq = (const float*)d_in[5];
  const float* Wk = (const float*)d_in[6];
  const float* Wv = (const float*)d_in[7];
  const float* W1 = (const float*)d_in[8];
  const float* W2 = (const float*)d_in[9];
  float* out = (float*)d_out;

  float* u = (float*)d_ws;
  float* v = u + (size_t)kB * kF;
  float* cb = v + (size_t)kB * kF;
  float* anorm = cb + kB;
  float* a = anorm + kB;
  unsigned short* w2p = (unsigned short*)(a + kN);  // 16-B aligned (checked)

  k_prepw<<<64, 256, 0, stream>>>(W2, w2p);
  k_precompute<<<kB, kF, 0, stream>>>(E, Wq, bq, Wk, Wv, u, v, cb, anorm);
  k_pass1<<<2048, 256, 0, stream>>>(x, seg, u, cb, a, anorm);
  k_pass2<<<768, 512, 0, stream>>>(seg, a, anorm, v, W1, w2p, out);
}

// Round 15
// 387.767 us; speedup vs baseline: 2.8187x; 2.8187x over previous
//
#include <hip/hip_runtime.h>

// Problem constants (from reference setup_inputs).
constexpr int kN = 1000000;   // rows
constexpr int kF = 128;       // features
constexpr int kB = 4096;      // batches

using short8 = __attribute__((ext_vector_type(8))) short;
using f32x4 = __attribute__((ext_vector_type(4))) float;

__device__ __forceinline__ unsigned short to_bf16(float f) {
  unsigned int u = __builtin_bit_cast(unsigned int, f);
  u += 0x7fffu + ((u >> 16) & 1u);  // RNE
  return (unsigned short)(u >> 16);
}

// One packed RNE f32->bf16 pair (lo -> bits[15:0], hi -> bits[31:16]).
__device__ __forceinline__ unsigned int cvt_pk_bf16(float lo, float hi) {
  unsigned int r;
  asm("v_cvt_pk_bf16_f32 %0, %1, %2" : "=v"(r) : "v"(lo), "v"(hi));
  return r;
}

__device__ __forceinline__ float silu_f(float z) {
  return z / (1.f + __expf(-z));
}

// ---------------- K0b: pre-permute W2 fragments to global bf16 ----------------
__global__ __launch_bounds__(256) void k_prepw(const float* __restrict__ W2,
                                               unsigned short* __restrict__ w2p) {
  const int idx = blockIdx.x * 256 + threadIdx.x;  // 16384 total
  const int i = idx & 7;
  const int l = (idx >> 3) & 63;
  const int kb = (idx >> 9) & 3;
  const int nb = (idx >> 11) & 7;
  const int cc = l & 15;
  const int col = kb * 32 + ((l >> 4) & 3) * 8 + i;
  const int row = (nb >> 1) * 32 + 2 * cc + (nb & 1);
  w2p[idx] = to_bf16(W2[row * kF + col]);
}

// ---------------- K1: per-batch precompute ----------------
__global__ __launch_bounds__(128) void k_precompute(
    const float* __restrict__ E, const float* __restrict__ Wq,
    const float* __restrict__ bq, const float* __restrict__ Wk,
    const float* __restrict__ Wv, float* __restrict__ u,
    float* __restrict__ v, float* __restrict__ cb,
    float* __restrict__ anorm) {
  __shared__ float ksh[kF];
  const int b = blockIdx.x;
  const int f = threadIdx.x;
  const float Eb = E[b];
  const float e0 = fmaxf(Eb, 0.f);
  const float e1 = fmaxf(-Eb, 0.f);
  const float en0 = e0 / fmaxf(e0, 1.f);
  const float en1 = e1 / fmaxf(e1, 1.f);
  const float kf = Wk[2 * f + 0] * en0 + Wk[2 * f + 1] * en1;
  const float vf = Wv[2 * f + 0] * e0 + Wv[2 * f + 1] * e1;
  v[b * kF + f] = vf;
  ksh[f] = kf;
  __syncthreads();
  float uj = 0.f;
#pragma unroll 8
  for (int ff = 0; ff < kF; ++ff) uj = fmaf(Wq[ff * kF + f], ksh[ff], uj);
  u[b * kF + f] = uj;
  if (f == 0) {
    float c = 0.f;
    for (int ff = 0; ff < kF; ++ff) c = fmaf(bq[ff], ksh[ff], c);
    cb[b] = c;
    anorm[b] = 0.f;
  }
}

// ---------------- K2: dot -> softplus -> segment sum ----------------
__global__ __launch_bounds__(256) void k_pass1(
    const float* __restrict__ x, const int* __restrict__ seg,
    const float* __restrict__ u, const float* __restrict__ cb,
    float* __restrict__ a, float* __restrict__ anorm) {
  const int lane = threadIdx.x & 63;
  const int g = lane >> 4;   // row within quad
  const int c = lane & 15;   // column chunk (8 floats)
  const int wave = (int)((blockIdx.x * blockDim.x + threadIdx.x) >> 6);
  const int nw = (int)((gridDim.x * blockDim.x) >> 6);
  const int cpw = (((kN + nw - 1) / nw) + 15) & ~15;  // multiple of 16
  const int r0 = wave * cpw;
  const int r1 = min(kN, r0 + cpw);
  int bacc = -1;
  float ssum = 0.f;
  for (int rb = r0; rb < r1; rb += 16) {
    float4 xa[4], xb[4], ua[4], ub[4];
    int b4[4];
#pragma unroll
    for (int q = 0; q < 4; ++q) {
      const int row = rb + 4 * q + g;
      const int b = seg[row];
      b4[q] = b;
      const float* xr = x + (size_t)row * kF + c * 8;
      const float* ur = u + (size_t)b * kF + c * 8;
      xa[q] = *reinterpret_cast<const float4*>(xr);
      xb[q] = *reinterpret_cast<const float4*>(xr + 4);
      ua[q] = *reinterpret_cast<const float4*>(ur);
      ub[q] = *reinterpret_cast<const float4*>(ur + 4);
    }
    float av4[4];
#pragma unroll
    for (int q = 0; q < 4; ++q) {
      float p = xa[q].x * ua[q].x;
      p = fmaf(xa[q].y, ua[q].y, p);
      p = fmaf(xa[q].z, ua[q].z, p);
      p = fmaf(xa[q].w, ua[q].w, p);
      p = fmaf(xb[q].x, ub[q].x, p);
      p = fmaf(xb[q].y, ub[q].y, p);
      p = fmaf(xb[q].z, ub[q].z, p);
      p = fmaf(xb[q].w, ub[q].w, p);
#pragma unroll
      for (int o = 1; o < 16; o <<= 1) p += __shfl_xor(p, o);
      const float dot = (p + cb[b4[q]]) * 0.08838834764831845f;  // 1/sqrt(128)
      const float av = fmaxf(dot, 0.f) + __logf(1.f + __expf(-fabsf(dot)));
      av4[q] = av;
      if (c == 0) a[rb + 4 * q + g] = av;
    }
    if (c == 0) {
#pragma unroll
      for (int q = 0; q < 4; ++q) {
        if (b4[q] != bacc) {
          if (bacc >= 0) atomicAdd(anorm + bacc, ssum);
          bacc = b4[q];
          ssum = 0.f;
        }
        ssum += av4[q];
      }
    }
  }
  if (c == 0 && bacc >= 0) atomicAdd(anorm + bacc, ssum);
}

// ---------------- K3: attn*v + residual MLP via bf16 MFMA ----------------
// R13 structure, W2 evicted to a pre-permuted global copy (L2-resident,
// lane-linear b128 loads). LDS/block = 32KB W1 + 10KB stg = 42KB ->
// 3 blocks/CU -> 24 waves/CU, PROVIDED natural VGPR stays <= 85.
// NO min-waves launch bound: R7 (64-reg cap) and R14 (forced 40 + 2GB of
// spill traffic) both proved caps below the natural ~84 are catastrophic.
constexpr int kWaves = 8;        // 512 threads
constexpr int kStg = 40;         // staging row stride in bf16

__global__ __launch_bounds__(512) void k_pass2(
    const int* __restrict__ seg, const float* __restrict__ a,
    const float* __restrict__ anorm, const float* __restrict__ v,
    const float* __restrict__ W1, const unsigned short* __restrict__ w2p,
    float* __restrict__ out) {
  __shared__ __align__(16) unsigned short Wf[16384];
  __shared__ __align__(16) unsigned short stg[kWaves][16 * kStg];
  const int tid = threadIdx.x;
  for (int idx = tid; idx < 16384; idx += 512) {
    const int i = idx & 7;
    const int l = (idx >> 3) & 63;
    const int kb = (idx >> 9) & 3;
    const int nb = (idx >> 11) & 7;
    const int cc = l & 15;
    const int col = kb * 32 + ((l >> 4) & 3) * 8 + i;
    const int row = (nb >> 1) * 32 + 2 * cc + (nb & 1);  // pair perm
    Wf[idx] = to_bf16(W1[row * kF + col]);
  }
  __syncthreads();

  const int wid = tid >> 6;
  const int lane = tid & 63;
  const int c = lane & 15;
  const int g = lane >> 4;
  unsigned short* __restrict__ st = stg[wid];

  const int gw = blockIdx.x * kWaves + wid;
  const int nw = gridDim.x * kWaves;
  const int niter = kN / 32;  // 31250

  for (int it = gw; it < niter; it += nw) {
    const int rbase = it * 32;
    const int blo = seg[rbase];
    const int bhi = seg[rbase + 31];
    const bool uni = (blo == bhi);   // wave-uniform branch

    int bb[2];
    float attn[2];
    short8 t1[2][4];

    if (uni) {
      const float an = anorm[blo] + 1e-8f;
      const float* vrow = v + (size_t)blo * kF;
      float4 va[4], vb[4];
#pragma unroll
      for (int kb = 0; kb < 4; ++kb) {
        const int k0 = kb * 32 + g * 8;
        va[kb] = *reinterpret_cast<const float4*>(vrow + k0);
        vb[kb] = *reinterpret_cast<const float4*>(vrow + k0 + 4);
      }
#pragma unroll
      for (int mt = 0; mt < 2; ++mt) {
        const int row = rbase + mt * 16 + c;
        const float at = a[row] / an;
        attn[mt] = at;
        bb[mt] = blo;
#pragma unroll
        for (int kb = 0; kb < 4; ++kb) {
          uint4 pk;
          pk.x = cvt_pk_bf16(silu_f(at * va[kb].x), silu_f(at * va[kb].y));
          pk.y = cvt_pk_bf16(silu_f(at * va[kb].z), silu_f(at * va[kb].w));
          pk.z = cvt_pk_bf16(silu_f(at * vb[kb].x), silu_f(at * vb[kb].y));
          pk.w = cvt_pk_bf16(silu_f(at * vb[kb].z), silu_f(at * vb[kb].w));
          t1[mt][kb] = __builtin_bit_cast(short8, pk);
        }
      }
    } else {
#pragma unroll
      for (int mt = 0; mt < 2; ++mt) {
        const int row = rbase + mt * 16 + c;
        const int b = seg[row];
        bb[mt] = b;
        const float at = a[row] / (anorm[b] + 1e-8f);
        attn[mt] = at;
        const float* vrow = v + (size_t)b * kF;
#pragma unroll
        for (int kb = 0; kb < 4; ++kb) {
          const int k0 = kb * 32 + g * 8;
          const float4 va = *reinterpret_cast<const float4*>(vrow + k0);
          const float4 vb = *reinterpret_cast<const float4*>(vrow + k0 + 4);
          uint4 pk;
          pk.x = cvt_pk_bf16(silu_f(at * va.x), silu_f(at * va.y));
          pk.y = cvt_pk_bf16(silu_f(at * va.z), silu_f(at * va.w));
          pk.z = cvt_pk_bf16(silu_f(at * vb.x), silu_f(at * vb.y));
          pk.w = cvt_pk_bf16(silu_f(at * vb.z), silu_f(at * vb.w));
          t1[mt][kb] = __builtin_bit_cast(short8, pk);
        }
      }
    }

    f32x4 acc2[2][8];
#pragma unroll
    for (int mt = 0; mt < 2; ++mt)
#pragma unroll
      for (int jb = 0; jb < 8; ++jb) acc2[mt][jb] = (f32x4){0.f, 0.f, 0.f, 0.f};

    __builtin_amdgcn_s_setprio(1);
#pragma unroll
    for (int p = 0; p < 4; ++p) {
      f32x4 z[2][2];
#pragma unroll
      for (int mt = 0; mt < 2; ++mt)
#pragma unroll
        for (int nb = 0; nb < 2; ++nb) z[mt][nb] = (f32x4){0.f, 0.f, 0.f, 0.f};
#pragma unroll
      for (int kb = 0; kb < 4; ++kb) {
        const short8 w0 = *reinterpret_cast<const short8*>(
            &Wf[(((2 * p + 0) * 4 + kb) * 64 + lane) * 8]);
        const short8 w1 = *reinterpret_cast<const short8*>(
            &Wf[(((2 * p + 1) * 4 + kb) * 64 + lane) * 8]);
        z[0][0] = __builtin_amdgcn_mfma_f32_16x16x32_bf16(t1[0][kb], w0,
                                                          z[0][0], 0, 0, 0);
        z[0][1] = __builtin_amdgcn_mfma_f32_16x16x32_bf16(t1[0][kb], w1,
                                                          z[0][1], 0, 0, 0);
        z[1][0] = __builtin_amdgcn_mfma_f32_16x16x32_bf16(t1[1][kb], w0,
                                                          z[1][0], 0, 0, 0);
        z[1][1] = __builtin_amdgcn_mfma_f32_16x16x32_bf16(t1[1][kb], w1,
                                                          z[1][1], 0, 0, 0);
      }
      // stage mt's t2 tile (features 32p+2c,+1 -> one u32), read A-frag,
      // then overwrite with the next mt (same-wave DS ops are in-order).
      short8 t2f[2];
#pragma unroll
      for (int mt = 0; mt < 2; ++mt) {
#pragma unroll
        for (int r = 0; r < 4; ++r) {
          const unsigned int pk =
              cvt_pk_bf16(silu_f(z[mt][0][r]), silu_f(z[mt][1][r]));
          *reinterpret_cast<unsigned int*>(
              &st[(g * 4 + r) * kStg + 2 * c]) = pk;
        }
        t2f[mt] =
            *reinterpret_cast<const short8*>(&st[c * kStg + g * 8]);
      }
#pragma unroll
      for (int jb = 0; jb < 8; ++jb) {
        const short8 w2f = *reinterpret_cast<const short8*>(
            &w2p[((jb * 4 + p) * 64 + lane) * 8]);
        acc2[0][jb] = __builtin_amdgcn_mfma_f32_16x16x32_bf16(t2f[0], w2f,
                                                              acc2[0][jb], 0, 0, 0);
        acc2[1][jb] = __builtin_amdgcn_mfma_f32_16x16x32_bf16(t2f[1], w2f,
                                                              acc2[1][jb], 0, 0, 0);
      }
    }
    __builtin_amdgcn_s_setprio(0);

    // epilogue: acc2[2q],acc2[2q+1] -> cols 32q+2c,32q+2c+1 (dwordx2 stores)
    if (uni) {
      const float* vrow = v + (size_t)blo * kF;
      float2 vep[4];
#pragma unroll
      for (int q = 0; q < 4; ++q)
        vep[q] = *reinterpret_cast<const float2*>(vrow + q * 32 + 2 * c);
#pragma unroll
      for (int mt = 0; mt < 2; ++mt) {
#pragma unroll
        for (int r = 0; r < 4; ++r) {
          const float at4 = __shfl(attn[mt], g * 4 + r);
          const int row = rbase + mt * 16 + g * 4 + r;
          float* orow = out + (size_t)row * kF;
#pragma unroll
          for (int q = 0; q < 4; ++q) {
            float2 o;
            o.x = fmaf(at4, vep[q].x, acc2[mt][2 * q + 0][r]);
            o.y = fmaf(at4, vep[q].y, acc2[mt][2 * q + 1][r]);
            *reinterpret_cast<float2*>(orow + q * 32 + 2 * c) = o;
          }
        }
      }
    } else {
#pragma unroll
      for (int mt = 0; mt < 2; ++mt) {
#pragma unroll
        for (int r = 0; r < 4; ++r) {
          const int b4 = __shfl(bb[mt], g * 4 + r);
          const float at4 = __shfl(attn[mt], g * 4 + r);
          const float* vr = v + (size_t)b4 * kF;
          const int row = rbase + mt * 16 + g * 4 + r;
          float* orow = out + (size_t)row * kF;
#pragma unroll
          for (int q = 0; q < 4; ++q) {
            const float2 vv =
                *reinterpret_cast<const float2*>(vr + q * 32 + 2 * c);
            float2 o;
            o.x = fmaf(at4, vv.x, acc2[mt][2 * q + 0][r]);
            o.y = fmaf(at4, vv.y, acc2[mt][2 * q + 1][r]);
            *reinterpret_cast<float2*>(orow + q * 32 + 2 * c) = o;
          }
        }
      }
    }
  }
}

extern "C" void kernel_launch(void* const* d_in, const int* in_sizes, int n_in,
                              void* d_out, int out_size, void* d_ws,
                              size_t ws_size, hipStream_t stream) {
  const float* x = (const float*)d_in[0];
  const float* E = (const float*)d_in[1];
  const int* seg = (const int*)d_in[3];
  const float* Wq = (const float*)d_in[4];
  const float* bq = (const float*)d_in[5];
  const float* Wk = (const float*)d_in[6];
  const float* Wv = (const float*)d_in[7];
  const float* W1 = (const float*)d_in[8];
  const float* W2 = (const float*)d_in[9];
  float* out = (float*)d_out;

  float* u = (float*)d_ws;
  float* v = u + (size_t)kB * kF;
  float* cb = v + (size_t)kB * kF;
  float* anorm = cb + kB;
  float* a = anorm + kB;
  unsigned short* w2p = (unsigned short*)(a + kN);  // 16-B aligned

  k_prepw<<<64, 256, 0, stream>>>(W2, w2p);
  k_precompute<<<kB, kF, 0, stream>>>(E, Wq, bq, Wk, Wv, u, v, cb, anorm);
  k_pass1<<<2048, 256, 0, stream>>>(x, seg, u, cb, a, anorm);
  k_pass2<<<768, 512, 0, stream>>>(seg, a, anorm, v, W1, w2p, out);
}

// Round 16
// 356.782 us; speedup vs baseline: 3.0635x; 1.0868x over previous
//
#include <hip/hip_runtime.h>

// Problem constants (from reference setup_inputs).
constexpr int kN = 1000000;   // rows
constexpr int kF = 128;       // features
constexpr int kB = 4096;      // batches

using short8 = __attribute__((ext_vector_type(8))) short;
using f32x4 = __attribute__((ext_vector_type(4))) float;

__device__ __forceinline__ unsigned short to_bf16(float f) {
  unsigned int u = __builtin_bit_cast(unsigned int, f);
  u += 0x7fffu + ((u >> 16) & 1u);  // RNE
  return (unsigned short)(u >> 16);
}

// One packed RNE f32->bf16 pair (lo -> bits[15:0], hi -> bits[31:16]).
__device__ __forceinline__ unsigned int cvt_pk_bf16(float lo, float hi) {
  unsigned int r;
  asm("v_cvt_pk_bf16_f32 %0, %1, %2" : "=v"(r) : "v"(lo), "v"(hi));
  return r;
}

__device__ __forceinline__ float silu_f(float z) {
  return z / (1.f + __expf(-z));
}

// ---------------- K1: per-batch precompute ----------------
__global__ __launch_bounds__(128) void k_precompute(
    const float* __restrict__ E, const float* __restrict__ Wq,
    const float* __restrict__ bq, const float* __restrict__ Wk,
    const float* __restrict__ Wv, float* __restrict__ u,
    float* __restrict__ v, float* __restrict__ cb,
    float* __restrict__ anorm) {
  __shared__ float ksh[kF];
  const int b = blockIdx.x;
  const int f = threadIdx.x;
  const float Eb = E[b];
  const float e0 = fmaxf(Eb, 0.f);
  const float e1 = fmaxf(-Eb, 0.f);
  const float en0 = e0 / fmaxf(e0, 1.f);
  const float en1 = e1 / fmaxf(e1, 1.f);
  const float kf = Wk[2 * f + 0] * en0 + Wk[2 * f + 1] * en1;
  const float vf = Wv[2 * f + 0] * e0 + Wv[2 * f + 1] * e1;
  v[b * kF + f] = vf;
  ksh[f] = kf;
  __syncthreads();
  float uj = 0.f;
#pragma unroll 8
  for (int ff = 0; ff < kF; ++ff) uj = fmaf(Wq[ff * kF + f], ksh[ff], uj);
  u[b * kF + f] = uj;
  if (f == 0) {
    float c = 0.f;
    for (int ff = 0; ff < kF; ++ff) c = fmaf(bq[ff], ksh[ff], c);
    cb[b] = c;
    anorm[b] = 0.f;
  }
}

// ---------------- K2: dot -> softplus -> segment sum ----------------
// 16 rows per wave-iteration (4 quads); per-group run accumulators.
__global__ __launch_bounds__(256) void k_pass1(
    const float* __restrict__ x, const int* __restrict__ seg,
    const float* __restrict__ u, const float* __restrict__ cb,
    float* __restrict__ a, float* __restrict__ anorm) {
  const int lane = threadIdx.x & 63;
  const int g = lane >> 4;   // row within quad
  const int c = lane & 15;   // column chunk (8 floats)
  const int wave = (int)((blockIdx.x * blockDim.x + threadIdx.x) >> 6);
  const int nw = (int)((gridDim.x * blockDim.x) >> 6);
  const int cpw = (((kN + nw - 1) / nw) + 15) & ~15;  // multiple of 16
  const int r0 = wave * cpw;
  const int r1 = min(kN, r0 + cpw);
  int bacc = -1;
  float ssum = 0.f;
  for (int rb = r0; rb < r1; rb += 16) {
    float4 xa[4], xb[4], ua[4], ub[4];
    int b4[4];
#pragma unroll
    for (int q = 0; q < 4; ++q) {
      const int row = rb + 4 * q + g;
      const int b = seg[row];
      b4[q] = b;
      const float* xr = x + (size_t)row * kF + c * 8;
      const float* ur = u + (size_t)b * kF + c * 8;
      xa[q] = *reinterpret_cast<const float4*>(xr);
      xb[q] = *reinterpret_cast<const float4*>(xr + 4);
      ua[q] = *reinterpret_cast<const float4*>(ur);
      ub[q] = *reinterpret_cast<const float4*>(ur + 4);
    }
    float av4[4];
#pragma unroll
    for (int q = 0; q < 4; ++q) {
      float p = xa[q].x * ua[q].x;
      p = fmaf(xa[q].y, ua[q].y, p);
      p = fmaf(xa[q].z, ua[q].z, p);
      p = fmaf(xa[q].w, ua[q].w, p);
      p = fmaf(xb[q].x, ub[q].x, p);
      p = fmaf(xb[q].y, ub[q].y, p);
      p = fmaf(xb[q].z, ub[q].z, p);
      p = fmaf(xb[q].w, ub[q].w, p);
#pragma unroll
      for (int o = 1; o < 16; o <<= 1) p += __shfl_xor(p, o);
      const float dot = (p + cb[b4[q]]) * 0.08838834764831845f;  // 1/sqrt(128)
      const float av = fmaxf(dot, 0.f) + __logf(1.f + __expf(-fabsf(dot)));
      av4[q] = av;
      if (c == 0) a[rb + 4 * q + g] = av;
    }
    if (c == 0) {
#pragma unroll
      for (int q = 0; q < 4; ++q) {
        if (b4[q] != bacc) {
          if (bacc >= 0) atomicAdd(anorm + bacc, ssum);
          bacc = b4[q];
          ssum = 0.f;
        }
        ssum += av4[q];
      }
    }
  }
  if (c == 0 && bacc >= 0) atomicAdd(anorm + bacc, ssum);
}

// ---------------- K3: attn*v + residual MLP via bf16 MFMA ----------------
// R12 config (512 thr, 2 blocks/CU, 16 waves/CU; W1 pair-perm + W2 natural
// in LDS; uniform-batch fast path; setprio; scalar epilogue) + software-
// pipelined p-loop: GEMM1(p+1) is issued between mt1's staging WRITE and
// its READ, so half the LDS round trips are covered by 16 MFMAs + the
// in-order DS queue. Costs one extra z set (+16 VGPR, budget 128 @ 4
// waves/SIMD -> occupancy unchanged).
constexpr int kWaves = 8;        // 512 threads
constexpr int kStg = 40;         // staging row stride in bf16

__global__ __launch_bounds__(512) void k_pass2(
    const int* __restrict__ seg, const float* __restrict__ a,
    const float* __restrict__ anorm, const float* __restrict__ v,
    const float* __restrict__ W1, const float* __restrict__ W2,
    float* __restrict__ out) {
  __shared__ __align__(16) unsigned short Wf[2 * 16384];
  __shared__ __align__(16) unsigned short stg[kWaves][16 * kStg];
  const int tid = threadIdx.x;
  for (int idx = tid; idx < 2 * 16384; idx += 512) {
    const int mtx = idx >> 14;
    const int e = idx & 16383;
    const int i = e & 7;
    const int l = (e >> 3) & 63;
    const int kb = (e >> 9) & 3;
    const int nb = (e >> 11) & 7;
    const int cc = l & 15;
    const int col = kb * 32 + ((l >> 4) & 3) * 8 + i;
    const int row = mtx ? (nb * 16 + cc)                        // W2: natural
                        : ((nb >> 1) * 32 + 2 * cc + (nb & 1)); // W1: pair perm
    const float w = (mtx ? W2 : W1)[row * kF + col];
    Wf[idx] = to_bf16(w);
  }
  __syncthreads();

  const int wid = tid >> 6;
  const int lane = tid & 63;
  const int c = lane & 15;
  const int g = lane >> 4;
  unsigned short* __restrict__ st = stg[wid];

  const int gw = blockIdx.x * kWaves + wid;
  const int nw = gridDim.x * kWaves;
  const int niter = kN / 32;  // 31250

  for (int it = gw; it < niter; it += nw) {
    const int rbase = it * 32;
    const int blo = seg[rbase];
    const int bhi = seg[rbase + 31];
    const bool uni = (blo == bhi);   // wave-uniform branch

    int bb[2];
    float attn[2];
    short8 t1[2][4];
    float vep[8];  // uniform-path epilogue v values (cols jb*16+c)

    if (uni) {
      const float an = anorm[blo] + 1e-8f;
      const float* vrow = v + (size_t)blo * kF;
      float4 va[4], vb[4];
#pragma unroll
      for (int kb = 0; kb < 4; ++kb) {
        const int k0 = kb * 32 + g * 8;
        va[kb] = *reinterpret_cast<const float4*>(vrow + k0);
        vb[kb] = *reinterpret_cast<const float4*>(vrow + k0 + 4);
      }
#pragma unroll
      for (int jb = 0; jb < 8; ++jb) vep[jb] = vrow[jb * 16 + c];
#pragma unroll
      for (int mt = 0; mt < 2; ++mt) {
        const int row = rbase + mt * 16 + c;
        const float at = a[row] / an;
        attn[mt] = at;
        bb[mt] = blo;
#pragma unroll
        for (int kb = 0; kb < 4; ++kb) {
          uint4 pk;
          pk.x = cvt_pk_bf16(silu_f(at * va[kb].x), silu_f(at * va[kb].y));
          pk.y = cvt_pk_bf16(silu_f(at * va[kb].z), silu_f(at * va[kb].w));
          pk.z = cvt_pk_bf16(silu_f(at * vb[kb].x), silu_f(at * vb[kb].y));
          pk.w = cvt_pk_bf16(silu_f(at * vb[kb].z), silu_f(at * vb[kb].w));
          t1[mt][kb] = __builtin_bit_cast(short8, pk);
        }
      }
    } else {
#pragma unroll
      for (int mt = 0; mt < 2; ++mt) {
        const int row = rbase + mt * 16 + c;
        const int b = seg[row];
        bb[mt] = b;
        const float at = a[row] / (anorm[b] + 1e-8f);
        attn[mt] = at;
        const float* vrow = v + (size_t)b * kF;
#pragma unroll
        for (int kb = 0; kb < 4; ++kb) {
          const int k0 = kb * 32 + g * 8;
          const float4 va = *reinterpret_cast<const float4*>(vrow + k0);
          const float4 vb = *reinterpret_cast<const float4*>(vrow + k0 + 4);
          uint4 pk;
          pk.x = cvt_pk_bf16(silu_f(at * va.x), silu_f(at * va.y));
          pk.y = cvt_pk_bf16(silu_f(at * va.z), silu_f(at * va.w));
          pk.z = cvt_pk_bf16(silu_f(at * vb.x), silu_f(at * vb.y));
          pk.w = cvt_pk_bf16(silu_f(at * vb.z), silu_f(at * vb.w));
          t1[mt][kb] = __builtin_bit_cast(short8, pk);
        }
      }
    }

    f32x4 acc2[2][8];
#pragma unroll
    for (int mt = 0; mt < 2; ++mt)
#pragma unroll
      for (int jb = 0; jb < 8; ++jb) acc2[mt][jb] = (f32x4){0.f, 0.f, 0.f, 0.f};

    __builtin_amdgcn_s_setprio(1);

    // ---- GEMM1 for p=0 (prologue) ----
    f32x4 zc[2][2];
#pragma unroll
    for (int mt = 0; mt < 2; ++mt)
#pragma unroll
      for (int nb = 0; nb < 2; ++nb) zc[mt][nb] = (f32x4){0.f, 0.f, 0.f, 0.f};
#pragma unroll
    for (int kb = 0; kb < 4; ++kb) {
      const short8 w0 = *reinterpret_cast<const short8*>(
          &Wf[((0 * 4 + kb) * 64 + lane) * 8]);
      const short8 w1 = *reinterpret_cast<const short8*>(
          &Wf[((1 * 4 + kb) * 64 + lane) * 8]);
      zc[0][0] = __builtin_amdgcn_mfma_f32_16x16x32_bf16(t1[0][kb], w0,
                                                         zc[0][0], 0, 0, 0);
      zc[0][1] = __builtin_amdgcn_mfma_f32_16x16x32_bf16(t1[0][kb], w1,
                                                         zc[0][1], 0, 0, 0);
      zc[1][0] = __builtin_amdgcn_mfma_f32_16x16x32_bf16(t1[1][kb], w0,
                                                         zc[1][0], 0, 0, 0);
      zc[1][1] = __builtin_amdgcn_mfma_f32_16x16x32_bf16(t1[1][kb], w1,
                                                         zc[1][1], 0, 0, 0);
    }

#pragma unroll
    for (int p = 0; p < 4; ++p) {
      short8 t2f0, t2f1;
      // stage mt0(p), read (exposed round trip)
#pragma unroll
      for (int r = 0; r < 4; ++r) {
        const unsigned int pk =
            cvt_pk_bf16(silu_f(zc[0][0][r]), silu_f(zc[0][1][r]));
        *reinterpret_cast<unsigned int*>(&st[(g * 4 + r) * kStg + 2 * c]) = pk;
      }
      t2f0 = *reinterpret_cast<const short8*>(&st[c * kStg + g * 8]);
      // stage mt1(p)
#pragma unroll
      for (int r = 0; r < 4; ++r) {
        const unsigned int pk =
            cvt_pk_bf16(silu_f(zc[1][0][r]), silu_f(zc[1][1][r]));
        *reinterpret_cast<unsigned int*>(&st[(g * 4 + r) * kStg + 2 * c]) = pk;
      }
      // GEMM1(p+1) between mt1's write and read: 8 b128 reads + 16 MFMAs
      // cover the round trip via the in-order DS queue.
      f32x4 zn[2][2];
      if (p < 3) {
#pragma unroll
        for (int mt = 0; mt < 2; ++mt)
#pragma unroll
          for (int nb = 0; nb < 2; ++nb)
            zn[mt][nb] = (f32x4){0.f, 0.f, 0.f, 0.f};
#pragma unroll
        for (int kb = 0; kb < 4; ++kb) {
          const short8 w0 = *reinterpret_cast<const short8*>(
              &Wf[(((2 * (p + 1) + 0) * 4 + kb) * 64 + lane) * 8]);
          const short8 w1 = *reinterpret_cast<const short8*>(
              &Wf[(((2 * (p + 1) + 1) * 4 + kb) * 64 + lane) * 8]);
          zn[0][0] = __builtin_amdgcn_mfma_f32_16x16x32_bf16(t1[0][kb], w0,
                                                             zn[0][0], 0, 0, 0);
          zn[0][1] = __builtin_amdgcn_mfma_f32_16x16x32_bf16(t1[0][kb], w1,
                                                             zn[0][1], 0, 0, 0);
          zn[1][0] = __builtin_amdgcn_mfma_f32_16x16x32_bf16(t1[1][kb], w0,
                                                             zn[1][0], 0, 0, 0);
          zn[1][1] = __builtin_amdgcn_mfma_f32_16x16x32_bf16(t1[1][kb], w1,
                                                             zn[1][1], 0, 0, 0);
        }
      }
      t2f1 = *reinterpret_cast<const short8*>(&st[c * kStg + g * 8]);
      // GEMM2(p)
#pragma unroll
      for (int jb = 0; jb < 8; ++jb) {
        const short8 w2f = *reinterpret_cast<const short8*>(
            &Wf[16384 + ((jb * 4 + p) * 64 + lane) * 8]);
        acc2[0][jb] = __builtin_amdgcn_mfma_f32_16x16x32_bf16(t2f0, w2f,
                                                              acc2[0][jb], 0, 0, 0);
        acc2[1][jb] = __builtin_amdgcn_mfma_f32_16x16x32_bf16(t2f1, w2f,
                                                              acc2[1][jb], 0, 0, 0);
      }
      if (p < 3) {
#pragma unroll
        for (int mt = 0; mt < 2; ++mt)
#pragma unroll
          for (int nb = 0; nb < 2; ++nb) zc[mt][nb] = zn[mt][nb];
      }
    }
    __builtin_amdgcn_s_setprio(0);

    // epilogue (R12 scalar form): out = attn*v + res, written from D-layout
    if (uni) {
#pragma unroll
      for (int mt = 0; mt < 2; ++mt) {
#pragma unroll
        for (int r = 0; r < 4; ++r) {
          const float at4 = __shfl(attn[mt], g * 4 + r);
          const int row = rbase + mt * 16 + g * 4 + r;
          float* orow = out + (size_t)row * kF;
#pragma unroll
          for (int jb = 0; jb < 8; ++jb) {
            orow[jb * 16 + c] = fmaf(at4, vep[jb], acc2[mt][jb][r]);
          }
        }
      }
    } else {
#pragma unroll
      for (int mt = 0; mt < 2; ++mt) {
        int b4[4];
        float at4[4];
#pragma unroll
        for (int r = 0; r < 4; ++r) {
          b4[r] = __shfl(bb[mt], g * 4 + r);
          at4[r] = __shfl(attn[mt], g * 4 + r);
        }
#pragma unroll
        for (int jb = 0; jb < 8; ++jb) {
#pragma unroll
          for (int r = 0; r < 4; ++r) {
            const int row = rbase + mt * 16 + g * 4 + r;
            const int col = jb * 16 + c;
            const float vv = v[(size_t)b4[r] * kF + col];
            out[(size_t)row * kF + col] = fmaf(at4[r], vv, acc2[mt][jb][r]);
          }
        }
      }
    }
  }
}

extern "C" void kernel_launch(void* const* d_in, const int* in_sizes, int n_in,
                              void* d_out, int out_size, void* d_ws,
                              size_t ws_size, hipStream_t stream) {
  const float* x = (const float*)d_in[0];
  const float* E = (const float*)d_in[1];
  const int* seg = (const int*)d_in[3];
  const float* Wq = (const float*)d_in[4];
  const float* bq = (const float*)d_in[5];
  const float* Wk = (const float*)d_in[6];
  const float* Wv = (const float*)d_in[7];
  const float* W1 = (const float*)d_in[8];
  const float* W2 = (const float*)d_in[9];
  float* out = (float*)d_out;

  float* u = (float*)d_ws;
  float* v = u + (size_t)kB * kF;
  float* cb = v + (size_t)kB * kF;
  float* anorm = cb + kB;
  float* a = anorm + kB;

  k_precompute<<<kB, kF, 0, stream>>>(E, Wq, bq, Wk, Wv, u, v, cb, anorm);
  k_pass1<<<2048, 256, 0, stream>>>(x, seg, u, cb, a, anorm);
  k_pass2<<<512, 512, 0, stream>>>(seg, a, anorm, v, W1, W2, out);
}